// Round 5
// baseline (424.579 us; speedup 1.0000x reference)
//
#include <hip/hip_runtime.h>
#include <math.h>

#define BATCH 16
#define P 32768
#define C 81
#define CM1 80
#define NCAND 400
#define NOUT 100
#define NBINS 256
#define SMIN_F (-3.0f)
#define BIN_SCALE (NBINS / 3.0f)
#define CAND_MAX 4096
#define SORTN 1024
#define IMG_SZ 512.0f
#define NMS_THR 0.45f
#define NWORDS 7
#define NPAD 448
#define RPB 64  // rows per block in the streaming passes

// ---- workspace layout (bytes) ----
#define OFF_HIST 0                                   // BATCH*NBINS*4 = 16384
#define OFF_CNT  (OFF_HIST + BATCH * NBINS * 4)      // 64
#define OFF_CVAL (OFF_CNT + 128)                     // BATCH*CAND_MAX*4
#define OFF_CIDX (OFF_CVAL + BATCH * CAND_MAX * 4)
#define OFF_MAXSC (OFF_CIDX + BATCH * CAND_MAX * 4)  // BATCH*P*4 = 2 MB
#define NEED_FAST (OFF_MAXSC + (size_t)BATCH * P * 4)

__device__ __forceinline__ int score_bin(float sc) {
    int b = (int)((sc - SMIN_F) * BIN_SCALE);
    return b < 0 ? 0 : (b > NBINS - 1 ? NBINS - 1 : b);
}

// Quad-per-row stats. MUST be bit-identical between k_hist (LDS source) and
// k_collect (global source): lane q of a 4-lane quad holds columns c = 4k+q,
// reductions via xor-1/xor-2. Same values + same order -> same bits.
__device__ __forceinline__ void quad_stats(const float* __restrict__ rowp, int q,
                                           float r[21], float& m, float& l, float& fg) {
#pragma unroll
    for (int k = 0; k < 21; ++k) {
        int c = 4 * k + q;
        r[k] = (c < C) ? rowp[c] : -INFINITY;
    }
    float mm = -INFINITY;
#pragma unroll
    for (int k = 0; k < 21; ++k) mm = fmaxf(mm, r[k]);
    mm = fmaxf(mm, __shfl_xor(mm, 1));
    mm = fmaxf(mm, __shfl_xor(mm, 2));
    float s = 0.0f;
#pragma unroll
    for (int k = 0; k < 21; ++k) {
        int c = 4 * k + q;
        if (c < C) s += __expf(r[k] - mm);
    }
    s += __shfl_xor(s, 1);
    s += __shfl_xor(s, 2);
    float fgm = -INFINITY;
#pragma unroll
    for (int k = 0; k < 21; ++k) {
        int c = 4 * k + q;
        if (c >= 1 && c < C) fgm = fmaxf(fgm, r[k]);
    }
    fgm = fmaxf(fgm, __shfl_xor(fgm, 1));
    fgm = fmaxf(fgm, __shfl_xor(fgm, 2));
    m = mm;
    l = __logf(s);
    fg = fgm;
}

// ---- pass 1: linear float4 staging into LDS (64 rows = 20736 B, aligned),
// then quad-per-row stats from LDS. 256 threads, 20.7 KB LDS -> ~28 waves/CU.
__global__ __launch_bounds__(256) void k_hist(const float* __restrict__ logits,
                                              unsigned* __restrict__ hist,
                                              float* __restrict__ maxsc,
                                              int write_maxsc) {
    __shared__ float tile[RPB * C];  // 20736 B
    __shared__ unsigned lh[NBINS];   // 1 KB
    int img = blockIdx.y;
    int row0 = blockIdx.x * RPB;
    lh[threadIdx.x] = 0;  // NBINS == blockDim
    // block base offset = row0*C*4 = blockIdx.x*20736 bytes -> 16B aligned
    const float4* g4 = (const float4*)(logits + ((size_t)img * P + row0) * C);
    float4* t4 = (float4*)tile;
#pragma unroll
    for (int i = 0; i < 6; ++i) {
        int idx = threadIdx.x + i * 256;
        if (idx < RPB * C / 4) t4[idx] = g4[idx];
    }
    __syncthreads();
    int quad = threadIdx.x >> 2, q = threadIdx.x & 3;
    const float* rowp = tile + quad * C;
    float r[21], m, l, fg;
    quad_stats(rowp, q, r, m, l, fg);
    if (write_maxsc && q == 0) maxsc[(size_t)img * P + row0 + quad] = (fg - m) - l;
#pragma unroll
    for (int k = 0; k < 21; ++k) {
        int c = 4 * k + q;
        if (c >= 1 && c < C) {
            float sc = (r[k] - m) - l;
            if (sc > SMIN_F) atomicAdd(&lh[score_bin(sc)], 1u);
        }
    }
    __syncthreads();
    unsigned h = lh[threadIdx.x];
    if (h) atomicAdd(&hist[(size_t)img * NBINS + threadIdx.x], h);
}

// ---- pass 2: per-block threshold from hist suffix-sum, then sparse re-read of
// qualifying rows only (~1.3% of rows via maxsc filter).
__global__ __launch_bounds__(256) void k_collect(const float* __restrict__ logits,
                                                 const unsigned* __restrict__ hist,
                                                 const float* __restrict__ maxsc,
                                                 int use_maxsc,
                                                 unsigned* __restrict__ cnt,
                                                 float* __restrict__ cval,
                                                 unsigned* __restrict__ cidx) {
    __shared__ unsigned sh[NBINS];
    __shared__ int tb_sh;
    int img = blockIdx.y;
    int b = threadIdx.x;
    sh[b] = hist[(size_t)img * NBINS + b];
    if (b == 0) tb_sh = 0;
    __syncthreads();
#pragma unroll
    for (int st = 1; st < NBINS; st <<= 1) {
        unsigned v = sh[b] + ((b + st < NBINS) ? sh[b + st] : 0u);
        __syncthreads();
        sh[b] = v;
        __syncthreads();
    }
    if (sh[b] >= NCAND) atomicMax(&tb_sh, b);
    __syncthreads();
    int tb = tb_sh;

    int quad = threadIdx.x >> 2, q = threadIdx.x & 3;
    int row = blockIdx.x * RPB + quad;
    bool qual = true;
    if (use_maxsc) {
        float ms = maxsc[(size_t)img * P + row];
        qual = (ms > SMIN_F) && (score_bin(ms) >= tb);
    }
    if (qual) {
        const float* rowp = logits + ((size_t)img * P + row) * C;
        float r[21], m, l, fg;
        quad_stats(rowp, q, r, m, l, fg);
#pragma unroll
        for (int k = 0; k < 21; ++k) {
            int c = 4 * k + q;
            if (c >= 1 && c < C) {
                float sc = (r[k] - m) - l;
                if (sc > SMIN_F && score_bin(sc) >= tb) {
                    unsigned pos = atomicAdd(&cnt[img], 1u);
                    if (pos < CAND_MAX) {
                        cval[(size_t)img * CAND_MAX + pos] = sc;
                        cidx[(size_t)img * CAND_MAX + pos] = (unsigned)(row * CM1 + c - 1);
                    }
                }
            }
        }
    }
}

__device__ __forceinline__ unsigned long long rdlane64(unsigned long long v, int lane) {
    int lo = __builtin_amdgcn_readlane((int)(unsigned)v, lane);
    int hi = __builtin_amdgcn_readlane((int)(unsigned)(v >> 32), lane);
    return ((unsigned long long)(unsigned)hi << 32) | (unsigned)lo;
}

__global__ __launch_bounds__(1024) void k_nms(const float* __restrict__ bbox,
                                              const float* __restrict__ priors,
                                              const unsigned* __restrict__ cnt,
                                              const float* __restrict__ cval,
                                              const unsigned* __restrict__ cidx,
                                              float* __restrict__ out) {
    __shared__ unsigned long long key[SORTN];
    __shared__ float x1[NCAND], y1[NCAND], x2[NCAND], y2[NCAND];
    __shared__ float ox1[NPAD], oy1[NPAD], ox2[NPAD], oy2[NPAD], areas[NPAD];
    __shared__ float scs[NCAND];
    __shared__ int lab[NCAND];
    __shared__ unsigned long long M[NPAD][NWORDS];
    __shared__ unsigned long long keepw_s[NWORDS];
    __shared__ int wpre_s[NWORDS + 1];
    __shared__ float wred[16];
    __shared__ float maxc_sh;
    __shared__ int kidx[NOUT];

    int img = blockIdx.x;
    int tid = threadIdx.x;
    int lane = tid & 63;
    int wv = tid >> 6;

    unsigned n = cnt[img];
    if (n > SORTN) n = SORTN;
    {
        float v;
        unsigned id;
        if ((unsigned)tid < n) {
            v = cval[(size_t)img * CAND_MAX + tid];
            id = cidx[(size_t)img * CAND_MAX + tid];
        } else {
            v = -INFINITY;
            id = 0x7FFFFFFFu;
        }
        unsigned bits = __float_as_uint(v);
        unsigned u = (bits & 0x80000000u) ? ~bits : (bits | 0x80000000u);
        key[tid] = ((unsigned long long)(~u) << 32) | id;  // asc key == desc val, asc idx
    }
    __syncthreads();

    for (int k2 = 2; k2 <= SORTN; k2 <<= 1) {
        for (int j = k2 >> 1; j > 0; j >>= 1) {
            int l = tid ^ j;
            if (l > tid) {
                unsigned long long a = key[tid], bb = key[l];
                bool up = ((tid & k2) == 0);
                if ((a > bb) == up) { key[tid] = bb; key[l] = a; }
            }
            __syncthreads();
        }
    }

    if (tid < NCAND) {
        unsigned long long kk = key[tid];
        unsigned uu = ~(unsigned)(kk >> 32);
        unsigned bits = (uu & 0x80000000u) ? (uu & 0x7FFFFFFFu) : ~uu;
        scs[tid] = __uint_as_float(bits);
        unsigned f = (unsigned)(kk & 0xFFFFFFFFu);
        if (f > (unsigned)(P * CM1 - 1)) f = (unsigned)(P * CM1 - 1);
        int p = (int)(f / CM1);
        int c = (int)(f % CM1) + 1;
        const float* lp = bbox + ((size_t)img * P + p) * 4;
        const float* pp = priors + (size_t)p * 4;
        float cx = lp[0] * 0.1f * pp[2] + pp[0];
        float cy = lp[1] * 0.1f * pp[3] + pp[1];
        float w = expf(lp[2] * 0.2f) * pp[2];
        float h = expf(lp[3] * 0.2f) * pp[3];
        x1[tid] = (cx - w * 0.5f) * IMG_SZ;
        y1[tid] = (cy - h * 0.5f) * IMG_SZ;
        x2[tid] = (cx + w * 0.5f) * IMG_SZ;
        y2[tid] = (cy + h * 0.5f) * IMG_SZ;
        lab[tid] = c;
    }
    __syncthreads();

    float m = -INFINITY;
    if (tid < NCAND) m = fmaxf(fmaxf(x1[tid], y1[tid]), fmaxf(x2[tid], y2[tid]));
#pragma unroll
    for (int off = 32; off >= 1; off >>= 1) m = fmaxf(m, __shfl_xor(m, off));
    if (lane == 0) wred[wv] = m;
    __syncthreads();
    if (tid == 0) {
        float mm = -INFINITY;
        for (int t = 0; t < 16; ++t) mm = fmaxf(mm, wred[t]);
        maxc_sh = mm;
    }
    __syncthreads();

    if (tid < NPAD) {
        if (tid < NCAND) {
            float off = (float)lab[tid] * (maxc_sh + 1.0f);
            ox1[tid] = x1[tid] + off;
            oy1[tid] = y1[tid] + off;
            ox2[tid] = x2[tid] + off;
            oy2[tid] = y2[tid] + off;
            areas[tid] = (ox2[tid] - ox1[tid]) * (oy2[tid] - oy1[tid]);
        } else {
            ox1[tid] = 1e30f; oy1[tid] = 1e30f;
            ox2[tid] = 1e30f; oy2[tid] = 1e30f;
            areas[tid] = 0.0f;
        }
    }
    __syncthreads();

    for (int i = wv; i < NCAND; i += 16) {
        float a1 = ox1[i], b1 = oy1[i], a2 = ox2[i], b2 = oy2[i], ar = areas[i];
#pragma unroll
        for (int wd = 0; wd < NWORDS; ++wd) {
            int j = wd * 64 + lane;
            float iw_ = fmaxf(fminf(a2, ox2[j]) - fmaxf(a1, ox1[j]), 0.0f);
            float ih_ = fmaxf(fminf(b2, oy2[j]) - fmaxf(b1, oy1[j]), 0.0f);
            float inter = iw_ * ih_;
            float uni = ar + areas[j] - inter;
            float iou = inter / fmaxf(uni, 1e-12f);
            unsigned long long bits = __ballot(iou > NMS_THR);
            if (lane == 0) M[i][wd] = bits;
        }
    }
    __syncthreads();

    if (wv == 0) {
        unsigned long long acc[NWORDS] = {0, 0, 0, 0, 0, 0, 0};
        unsigned long long keepw[NWORDS];
#pragma unroll
        for (int iw = 0; iw < NWORDS; ++iw) {
            unsigned long long mrow[NWORDS];
#pragma unroll
            for (int w = 0; w < NWORDS; ++w) mrow[w] = M[iw * 64 + lane][w];
            unsigned long long sup = acc[iw];
            unsigned long long K = 0;
            int nb = (iw == NWORDS - 1) ? (NCAND - 64 * (NWORDS - 1)) : 64;
            for (int ib = 0; ib < nb; ++ib) {
                if (!((sup >> ib) & 1ull)) {
                    K |= (1ull << ib);
                    sup |= rdlane64(mrow[iw], ib);
#pragma unroll
                    for (int w = 0; w < NWORDS; ++w) acc[w] |= rdlane64(mrow[w], ib);
                }
            }
            keepw[iw] = K;
        }
        if (lane == 0) {
            int a = 0;
#pragma unroll
            for (int w = 0; w < NWORDS; ++w) {
                keepw_s[w] = keepw[w];
                wpre_s[w] = a;
                a += __popcll(keepw[w]);
            }
            wpre_s[NWORDS] = a;
        }
    }
    __syncthreads();

    if (tid < NCAND) {
        int w = tid >> 6, bb = tid & 63;
        unsigned long long kwv = keepw_s[w];
        bool kp = (kwv >> bb) & 1ull;
        unsigned long long below_mask = (bb == 0) ? 0ull : (~0ull >> (64 - bb));
        int below = wpre_s[w] + __popcll(kwv & below_mask);
        int nkept = wpre_s[NWORDS];
        int pos = kp ? below : nkept + (tid - below);
        if (pos < NOUT) kidx[pos] = tid;
    }
    __syncthreads();

    if (tid < NOUT) {
        int i = kidx[tid];
        bool kp = (keepw_s[i >> 6] >> (i & 63)) & 1ull;
        float* ob = out + ((size_t)img * NOUT + tid) * 4;
        ob[0] = x1[i];
        ob[1] = y1[i];
        ob[2] = x2[i];
        ob[3] = y2[i];
        out[(size_t)BATCH * NOUT * 4 + (size_t)img * NOUT + tid] = (float)lab[i];
        out[(size_t)BATCH * NOUT * 4 + (size_t)BATCH * NOUT + (size_t)img * NOUT + tid] =
            kp ? scs[i] : -INFINITY;
    }
}

extern "C" void kernel_launch(void* const* d_in, const int* in_sizes, int n_in,
                              void* d_out, int out_size, void* d_ws, size_t ws_size,
                              hipStream_t stream) {
    const float* logits = (const float*)d_in[0];
    const float* bbox = (const float*)d_in[1];
    const float* priors = (const float*)d_in[2];
    float* out = (float*)d_out;
    char* ws = (char*)d_ws;

    unsigned* hist = (unsigned*)(ws + OFF_HIST);
    unsigned* cnt = (unsigned*)(ws + OFF_CNT);
    float* cval = (float*)(ws + OFF_CVAL);
    unsigned* cidx = (unsigned*)(ws + OFF_CIDX);
    float* maxsc = (float*)(ws + OFF_MAXSC);

    int fast = (ws_size >= NEED_FAST) ? 1 : 0;

    hipMemsetAsync(ws, 0, OFF_CVAL, stream);  // hist + cnt

    dim3 g1(P / RPB, BATCH);
    k_hist<<<g1, 256, 0, stream>>>(logits, hist, fast ? maxsc : (float*)ws, fast);
    k_collect<<<g1, 256, 0, stream>>>(logits, hist, maxsc, fast, cnt, cval, cidx);
    k_nms<<<BATCH, 1024, 0, stream>>>(bbox, priors, cnt, cval, cidx, out);
}

// Round 6
// 381.876 us; speedup vs baseline: 1.1118x; 1.1118x over previous
//
#include <hip/hip_runtime.h>
#include <math.h>

#define BATCH 16
#define P 32768
#define C 81
#define CM1 80
#define NCAND 400
#define NOUT 100
#define NBINS 256
#define SMIN_F (-3.0f)
#define BIN_SCALE (NBINS / 3.0f)
#define SORTN 1024
#define ROWCAP 1024
#define IMG_SZ 512.0f
#define NMS_THR 0.45f
#define NWORDS 7
#define NPAD 448
#define RPB 64  // rows per block in the streaming pass

// ---- workspace layout (bytes) ----
#define OFF_HIST 0                              // BATCH*NBINS*4 = 16384
#define OFF_MAXSC 16384                         // BATCH*P*4 = 2 MB (16B-aligned)
#define NEED_WS (OFF_MAXSC + (size_t)BATCH * P * 4)

__device__ __forceinline__ int score_bin(float sc) {
    int b = (int)((sc - SMIN_F) * BIN_SCALE);
    return b < 0 ? 0 : (b > NBINS - 1 ? NBINS - 1 : b);
}

// Quad-per-row stats. MUST be bit-identical between k_hist (LDS source) and
// k_post (global source): lane q of a 4-lane quad holds columns c = 4k+q,
// reductions via xor-1/xor-2. Same float values + same op order -> same bits.
__device__ __forceinline__ void quad_stats(const float* __restrict__ rowp, int q,
                                           float r[21], float& m, float& l, float& fg) {
#pragma unroll
    for (int k = 0; k < 21; ++k) {
        int c = 4 * k + q;
        r[k] = (c < C) ? rowp[c] : -INFINITY;
    }
    float mm = -INFINITY;
#pragma unroll
    for (int k = 0; k < 21; ++k) mm = fmaxf(mm, r[k]);
    mm = fmaxf(mm, __shfl_xor(mm, 1));
    mm = fmaxf(mm, __shfl_xor(mm, 2));
    float s = 0.0f;
#pragma unroll
    for (int k = 0; k < 21; ++k) {
        int c = 4 * k + q;
        if (c < C) s += __expf(r[k] - mm);
    }
    s += __shfl_xor(s, 1);
    s += __shfl_xor(s, 2);
    float fgm = -INFINITY;
#pragma unroll
    for (int k = 0; k < 21; ++k) {
        int c = 4 * k + q;
        if (c >= 1 && c < C) fgm = fmaxf(fgm, r[k]);
    }
    fgm = fmaxf(fgm, __shfl_xor(fgm, 1));
    fgm = fmaxf(fgm, __shfl_xor(fgm, 2));
    m = mm;
    l = __logf(s);
    fg = fgm;
}

__device__ __forceinline__ unsigned long long pack_key(float v, unsigned id) {
    unsigned bits = __float_as_uint(v);
    unsigned u = (bits & 0x80000000u) ? ~bits : (bits | 0x80000000u);
    return ((unsigned long long)(~u) << 32) | id;  // asc key == desc value, asc idx
}

// ---- pass 1: linear float4 staging into LDS, quad-per-row stats,
// histogram of scores > SMIN_F + per-row max score.
__global__ __launch_bounds__(256) void k_hist(const float* __restrict__ logits,
                                              unsigned* __restrict__ hist,
                                              float* __restrict__ maxsc) {
    __shared__ float tile[RPB * C];  // 20736 B
    __shared__ unsigned lh[NBINS];   // 1 KB
    int img = blockIdx.y;
    int row0 = blockIdx.x * RPB;
    lh[threadIdx.x] = 0;
    const float4* g4 = (const float4*)(logits + ((size_t)img * P + row0) * C);
    float4* t4 = (float4*)tile;
#pragma unroll
    for (int i = 0; i < 6; ++i) {
        int idx = threadIdx.x + i * 256;
        if (idx < RPB * C / 4) t4[idx] = g4[idx];
    }
    __syncthreads();
    int quad = threadIdx.x >> 2, q = threadIdx.x & 3;
    const float* rowp = tile + quad * C;
    float r[21], m, l, fg;
    quad_stats(rowp, q, r, m, l, fg);
    if (q == 0) maxsc[(size_t)img * P + row0 + quad] = (fg - m) - l;
#pragma unroll
    for (int k = 0; k < 21; ++k) {
        int c = 4 * k + q;
        if (c >= 1 && c < C) {
            float sc = (r[k] - m) - l;
            if (sc > SMIN_F) atomicAdd(&lh[score_bin(sc)], 1u);
        }
    }
    __syncthreads();
    unsigned h = lh[threadIdx.x];
    if (h) atomicAdd(&hist[(size_t)img * NBINS + threadIdx.x], h);
}

// ---- pass 2: one block per image. threshold -> row compact -> recompute ->
// sort -> decode -> IoU -> greedy NMS -> outputs.
__global__ __launch_bounds__(512) void k_post(const float* __restrict__ logits,
                                              const float* __restrict__ bbox,
                                              const float* __restrict__ priors,
                                              const unsigned* __restrict__ hist,
                                              const float* __restrict__ maxsc,
                                              float* __restrict__ out) {
    __shared__ unsigned sh[NBINS];
    __shared__ int tb_sh, nrows_sh, ncand_sh;
    __shared__ int rowlist[ROWCAP];
    __shared__ unsigned long long key[SORTN];
    __shared__ float x1[NCAND], y1[NCAND], x2[NCAND], y2[NCAND];
    __shared__ float ox1[NPAD], oy1[NPAD], ox2[NPAD], oy2[NPAD], areas[NPAD];
    __shared__ float scs[NCAND];
    __shared__ int lab[NCAND];
    __shared__ unsigned long long M[NPAD][NWORDS];
    __shared__ unsigned long long keepw_s[NWORDS];
    __shared__ int wpre_s[NWORDS + 1];
    __shared__ float wred[8];
    __shared__ float maxc_sh;
    __shared__ int kidx[NOUT];

    int img = blockIdx.x;
    int tid = threadIdx.x;
    int lane = tid & 63;
    int wv = tid >> 6;

    // threshold from histogram suffix-sum
    if (tid == 0) { tb_sh = 0; nrows_sh = 0; ncand_sh = 0; }
    if (tid < NBINS) sh[tid] = hist[(size_t)img * NBINS + tid];
    __syncthreads();
#pragma unroll
    for (int st = 1; st < NBINS; st <<= 1) {
        unsigned v = 0;
        if (tid < NBINS) v = sh[tid] + ((tid + st < NBINS) ? sh[tid + st] : 0u);
        __syncthreads();
        if (tid < NBINS) sh[tid] = v;
        __syncthreads();
    }
    if (tid < NBINS && sh[tid] >= NCAND) atomicMax(&tb_sh, tid);
    key[tid] = pack_key(-INFINITY, 0x7FFFFFFFu);
    key[tid + 512] = pack_key(-INFINITY, 0x7FFFFFFFu);
    __syncthreads();
    int tb = tb_sh;

    // compact qualifying rows (maxsc monotone-exact vs per-candidate filter)
    {
        const float4* ms4 = (const float4*)(maxsc + (size_t)img * P);
#pragma unroll
        for (int i = 0; i < P / 4 / 512; ++i) {
            float4 v4 = ms4[tid + i * 512];
            int rbase = (tid + i * 512) * 4;
            float vv[4] = {v4.x, v4.y, v4.z, v4.w};
#pragma unroll
            for (int j = 0; j < 4; ++j) {
                if (vv[j] > SMIN_F && score_bin(vv[j]) >= tb) {
                    int pos = atomicAdd(&nrows_sh, 1);
                    if (pos < ROWCAP) rowlist[pos] = rbase + j;
                }
            }
        }
    }
    __syncthreads();
    int nrows = nrows_sh;
    if (nrows > ROWCAP) nrows = ROWCAP;

    // recompute scores for qualifying rows only; emit sort keys
    {
        int quad = tid >> 2, q = tid & 3;  // 128 quads
        for (int base = 0; base < nrows; base += 128) {
            int ri = base + quad;
            if (ri < nrows) {
                int row = rowlist[ri];
                const float* rowp = logits + ((size_t)img * P + row) * C;
                float r[21], m, l, fg;
                quad_stats(rowp, q, r, m, l, fg);
#pragma unroll
                for (int k = 0; k < 21; ++k) {
                    int c = 4 * k + q;
                    if (c >= 1 && c < C) {
                        float sc = (r[k] - m) - l;
                        if (sc > SMIN_F && score_bin(sc) >= tb) {
                            int pos = atomicAdd(&ncand_sh, 1);
                            if (pos < SORTN)
                                key[pos] = pack_key(sc, (unsigned)(row * CM1 + c - 1));
                        }
                    }
                }
            }
        }
    }
    __syncthreads();

    // bitonic sort ascending on u64 keys (1024 elems, 512 threads)
    for (int k2 = 2; k2 <= SORTN; k2 <<= 1) {
        for (int j = k2 >> 1; j > 0; j >>= 1) {
            for (int t = tid; t < SORTN; t += 512) {
                int l = t ^ j;
                if (l > t) {
                    unsigned long long a = key[t], bb = key[l];
                    bool up = ((t & k2) == 0);
                    if ((a > bb) == up) { key[t] = bb; key[l] = a; }
                }
            }
            __syncthreads();
        }
    }

    // decode top-400
    if (tid < NCAND) {
        unsigned long long kk = key[tid];
        unsigned uu = ~(unsigned)(kk >> 32);
        unsigned bits = (uu & 0x80000000u) ? (uu & 0x7FFFFFFFu) : ~uu;
        scs[tid] = __uint_as_float(bits);
        unsigned f = (unsigned)(kk & 0xFFFFFFFFu);
        if (f > (unsigned)(P * CM1 - 1)) f = (unsigned)(P * CM1 - 1);
        int p = (int)(f / CM1);
        int c = (int)(f % CM1) + 1;
        const float* lp = bbox + ((size_t)img * P + p) * 4;
        const float* pp = priors + (size_t)p * 4;
        float cx = lp[0] * 0.1f * pp[2] + pp[0];
        float cy = lp[1] * 0.1f * pp[3] + pp[1];
        float w = expf(lp[2] * 0.2f) * pp[2];
        float h = expf(lp[3] * 0.2f) * pp[3];
        x1[tid] = (cx - w * 0.5f) * IMG_SZ;
        y1[tid] = (cy - h * 0.5f) * IMG_SZ;
        x2[tid] = (cx + w * 0.5f) * IMG_SZ;
        y2[tid] = (cy + h * 0.5f) * IMG_SZ;
        lab[tid] = c;
    }
    __syncthreads();

    float m = -INFINITY;
    if (tid < NCAND) m = fmaxf(fmaxf(x1[tid], y1[tid]), fmaxf(x2[tid], y2[tid]));
#pragma unroll
    for (int off = 32; off >= 1; off >>= 1) m = fmaxf(m, __shfl_xor(m, off));
    if (lane == 0) wred[wv] = m;
    __syncthreads();
    if (tid == 0) {
        float mm = -INFINITY;
        for (int t = 0; t < 8; ++t) mm = fmaxf(mm, wred[t]);
        maxc_sh = mm;
    }
    __syncthreads();

    if (tid < NPAD) {
        if (tid < NCAND) {
            float off = (float)lab[tid] * (maxc_sh + 1.0f);
            ox1[tid] = x1[tid] + off;
            oy1[tid] = y1[tid] + off;
            ox2[tid] = x2[tid] + off;
            oy2[tid] = y2[tid] + off;
            areas[tid] = (ox2[tid] - ox1[tid]) * (oy2[tid] - oy1[tid]);
        } else {
            ox1[tid] = 1e30f; oy1[tid] = 1e30f;
            ox2[tid] = 1e30f; oy2[tid] = 1e30f;
            areas[tid] = 0.0f;
        }
    }
    __syncthreads();

    // IoU masks via ballot (8 waves)
    for (int i = wv; i < NCAND; i += 8) {
        float a1 = ox1[i], b1 = oy1[i], a2 = ox2[i], b2 = oy2[i], ar = areas[i];
#pragma unroll
        for (int wd = 0; wd < NWORDS; ++wd) {
            int j = wd * 64 + lane;
            float iw_ = fmaxf(fminf(a2, ox2[j]) - fmaxf(a1, ox1[j]), 0.0f);
            float ih_ = fmaxf(fminf(b2, oy2[j]) - fmaxf(b1, oy1[j]), 0.0f);
            float inter = iw_ * ih_;
            float uni = ar + areas[j] - inter;
            float iou = inter / fmaxf(uni, 1e-12f);
            unsigned long long bits = __ballot(iou > NMS_THR);
            if (lane == 0) M[i][wd] = bits;
        }
    }
    __syncthreads();

    // greedy NMS: wave 0, M rows pre-distributed across lanes, readlane core
    if (wv == 0) {
        unsigned long long acc[NWORDS] = {0, 0, 0, 0, 0, 0, 0};
        unsigned long long keepw[NWORDS];
#pragma unroll
        for (int iw = 0; iw < NWORDS; ++iw) {
            unsigned long long mrow[NWORDS];
#pragma unroll
            for (int w = 0; w < NWORDS; ++w) mrow[w] = M[iw * 64 + lane][w];
            unsigned long long sup = acc[iw];
            unsigned long long K = 0;
            int nb = (iw == NWORDS - 1) ? (NCAND - 64 * (NWORDS - 1)) : 64;
            for (int ib = 0; ib < nb; ++ib) {
                if (!((sup >> ib) & 1ull)) {
                    K |= (1ull << ib);
                    int lo, hi;
                    lo = __builtin_amdgcn_readlane((int)(unsigned)mrow[iw], ib);
                    hi = __builtin_amdgcn_readlane((int)(unsigned)(mrow[iw] >> 32), ib);
                    sup |= ((unsigned long long)(unsigned)hi << 32) | (unsigned)lo;
#pragma unroll
                    for (int w = 0; w < NWORDS; ++w) {
                        lo = __builtin_amdgcn_readlane((int)(unsigned)mrow[w], ib);
                        hi = __builtin_amdgcn_readlane((int)(unsigned)(mrow[w] >> 32), ib);
                        acc[w] |= ((unsigned long long)(unsigned)hi << 32) | (unsigned)lo;
                    }
                }
            }
            keepw[iw] = K;
        }
        if (lane == 0) {
            int a = 0;
#pragma unroll
            for (int w = 0; w < NWORDS; ++w) {
                keepw_s[w] = keepw[w];
                wpre_s[w] = a;
                a += __popcll(keepw[w]);
            }
            wpre_s[NWORDS] = a;
        }
    }
    __syncthreads();

    // kidx: kept (ascending) then unkept (ascending)
    if (tid < NCAND) {
        int w = tid >> 6, bb = tid & 63;
        unsigned long long kwv = keepw_s[w];
        bool kp = (kwv >> bb) & 1ull;
        unsigned long long below_mask = (bb == 0) ? 0ull : (~0ull >> (64 - bb));
        int below = wpre_s[w] + __popcll(kwv & below_mask);
        int nkept = wpre_s[NWORDS];
        int pos = kp ? below : nkept + (tid - below);
        if (pos < NOUT) kidx[pos] = tid;
    }
    __syncthreads();

    if (tid < NOUT) {
        int i = kidx[tid];
        bool kp = (keepw_s[i >> 6] >> (i & 63)) & 1ull;
        float* ob = out + ((size_t)img * NOUT + tid) * 4;
        ob[0] = x1[i];
        ob[1] = y1[i];
        ob[2] = x2[i];
        ob[3] = y2[i];
        out[(size_t)BATCH * NOUT * 4 + (size_t)img * NOUT + tid] = (float)lab[i];
        out[(size_t)BATCH * NOUT * 4 + (size_t)BATCH * NOUT + (size_t)img * NOUT + tid] =
            kp ? scs[i] : -INFINITY;
    }
}

extern "C" void kernel_launch(void* const* d_in, const int* in_sizes, int n_in,
                              void* d_out, int out_size, void* d_ws, size_t ws_size,
                              hipStream_t stream) {
    const float* logits = (const float*)d_in[0];
    const float* bbox = (const float*)d_in[1];
    const float* priors = (const float*)d_in[2];
    float* out = (float*)d_out;
    char* ws = (char*)d_ws;

    unsigned* hist = (unsigned*)(ws + OFF_HIST);
    float* maxsc = (float*)(ws + OFF_MAXSC);

    hipMemsetAsync(ws, 0, OFF_MAXSC, stream);  // zero hist

    dim3 g1(P / RPB, BATCH);
    k_hist<<<g1, 256, 0, stream>>>(logits, hist, maxsc);
    k_post<<<BATCH, 512, 0, stream>>>(logits, bbox, priors, hist, maxsc, out);
}